// Round 1
// baseline (402.198 us; speedup 1.0000x reference)
//
#include <hip/hip_runtime.h>
#include <hip/hip_bf16.h>
#include <stdint.h>

typedef __bf16 bf16_t;
typedef __bf16 bf16x8 __attribute__((ext_vector_type(8)));
typedef float f32x4 __attribute__((ext_vector_type(4)));

#define S_TOK 8192
#define DIM   1280
#define NH    16
#define HD    80
#define LSEQ  1024
#define N_QKV 3840

// ---------------- fp32 -> bf16 convert (hidden_states) ----------------
__global__ __launch_bounds__(256) void k_conv_bf16(const float* __restrict__ in,
                                                   bf16_t* __restrict__ out) {
  int g = blockIdx.x * 256 + threadIdx.x;          // one thread per 8 elements
  const float4* p = reinterpret_cast<const float4*>(in) + (size_t)g * 2;
  float4 v0 = p[0], v1 = p[1];
  bf16x8 o;
  o[0] = (bf16_t)v0.x; o[1] = (bf16_t)v0.y; o[2] = (bf16_t)v0.z; o[3] = (bf16_t)v0.w;
  o[4] = (bf16_t)v1.x; o[5] = (bf16_t)v1.y; o[6] = (bf16_t)v1.z; o[7] = (bf16_t)v1.w;
  *reinterpret_cast<bf16x8*>(out + (size_t)g * 8) = o;
}

// ---------------- W [K][N] fp32 -> Wt [N][K] bf16 ----------------
__global__ __launch_bounds__(256) void k_transpose_bf16(const float* __restrict__ W,
                                                        bf16_t* __restrict__ Wt,
                                                        int K, int N) {
  __shared__ float tile[32][33];
  int n0 = blockIdx.x * 32, k0 = blockIdx.y * 32;
  int tx = threadIdx.x, ty = threadIdx.y;          // 32 x 8
#pragma unroll
  for (int j = 0; j < 32; j += 8)
    tile[ty + j][tx] = W[(size_t)(k0 + ty + j) * N + n0 + tx];
  __syncthreads();
#pragma unroll
  for (int j = 0; j < 32; j += 8)
    Wt[(size_t)(n0 + ty + j) * K + k0 + tx] = (bf16_t)tile[tx][ty + j];
}

// ---------------- GEMM: C[M][N] = A[M][K] @ Bt[N][K]^T + bias ----------------
// 128x128 tile, BK=64, 4 waves (2x2), each wave 64x64 via 4x4 16x16x32 MFMA frags.
template <bool OUT_BF16>
__global__ __launch_bounds__(256) void k_gemm_bt(const bf16_t* __restrict__ A,
                                                 const bf16_t* __restrict__ Bt,
                                                 const float* __restrict__ bias,
                                                 void* __restrict__ Cout,
                                                 int M, int N, int K) {
  __shared__ __align__(16) bf16_t As[128][72];     // pad: 144B stride, 2-way banks (free)
  __shared__ __align__(16) bf16_t Bs[128][72];
  const int nb = N >> 7;
  const int bm = blockIdx.x / nb, bn = blockIdx.x % nb;
  const int tid = threadIdx.x, lane = tid & 63, w = tid >> 6;
  const int wm = w >> 1, wn = w & 1;
  const int l15 = lane & 15, lg = lane >> 4;
  const f32x4 fz = {0.f, 0.f, 0.f, 0.f};
  f32x4 acc[4][4];
#pragma unroll
  for (int i = 0; i < 4; ++i)
#pragma unroll
    for (int j = 0; j < 4; ++j) acc[i][j] = fz;
  const size_t a0 = (size_t)(bm * 128) * K;
  const size_t b0 = (size_t)(bn * 128) * K;

  for (int k0 = 0; k0 < K; k0 += 64) {
    __syncthreads();
#pragma unroll
    for (int p = 0; p < 4; ++p) {                  // 1024 chunks of 8 bf16 per tile
      int c = tid + p * 256;
      int r = c >> 3, ch = c & 7;
      size_t go = (size_t)r * K + k0 + ch * 8;
      *reinterpret_cast<uint4*>(&As[r][ch * 8]) = *reinterpret_cast<const uint4*>(A + a0 + go);
      *reinterpret_cast<uint4*>(&Bs[r][ch * 8]) = *reinterpret_cast<const uint4*>(Bt + b0 + go);
    }
    __syncthreads();
#pragma unroll
    for (int kk = 0; kk < 2; ++kk) {
      const int krow = kk * 32 + (lg << 3);
      bf16x8 af[4], bfv[4];
#pragma unroll
      for (int mf = 0; mf < 4; ++mf)
        af[mf] = *reinterpret_cast<const bf16x8*>(&As[wm * 64 + mf * 16 + l15][krow]);
#pragma unroll
      for (int nf = 0; nf < 4; ++nf)
        bfv[nf] = *reinterpret_cast<const bf16x8*>(&Bs[wn * 64 + nf * 16 + l15][krow]);
#pragma unroll
      for (int mf = 0; mf < 4; ++mf)
#pragma unroll
        for (int nf = 0; nf < 4; ++nf)
          acc[mf][nf] = __builtin_amdgcn_mfma_f32_16x16x32_bf16(af[mf], bfv[nf], acc[mf][nf], 0, 0, 0);
    }
  }
  // epilogue: D layout col = lane&15, row = (lane>>4)*4 + r
  const int rg = lg << 2;
#pragma unroll
  for (int nf = 0; nf < 4; ++nf) {
    const int col = bn * 128 + wn * 64 + nf * 16 + l15;
    const float bv = bias[col];
#pragma unroll
    for (int mf = 0; mf < 4; ++mf) {
      const int row0 = bm * 128 + wm * 64 + mf * 16 + rg;
#pragma unroll
      for (int r = 0; r < 4; ++r) {
        float v = acc[mf][nf][r] + bv;
        if (OUT_BF16)
          reinterpret_cast<bf16_t*>(Cout)[(size_t)(row0 + r) * N + col] = (bf16_t)v;
        else
          reinterpret_cast<float*>(Cout)[(size_t)(row0 + r) * N + col] = v;
      }
    }
  }
}

// ---------------- RoPE (in-place on q,k of qkv [S][3840]) ----------------
__global__ __launch_bounds__(256) void k_rope(bf16_t* __restrict__ qkv,
                                              const float* __restrict__ cosT,
                                              const float* __restrict__ sinT) {
  int g = blockIdx.x * 256 + threadIdx.x;          // g = s*80 + h*5 + c
  int c = g % 5;
  int h = (g / 5) & 15;
  int s = g / 80;
  const int d0 = c * 8;                            // d0 in [0,40)
  float cs[8], sn[8];
#pragma unroll
  for (int j = 0; j < 8; ++j) {
    cs[j] = cosT[s * 80 + d0 + j];
    sn[j] = sinT[s * 80 + d0 + j];                 // cos/sin duplicated across halves
  }
  size_t base = (size_t)s * N_QKV + h * 80 + d0;
#pragma unroll
  for (int part = 0; part < 2; ++part) {           // q then k
    bf16_t* p0 = qkv + base + part * 1280;
    bf16_t* p1 = p0 + 40;
    bf16x8 a = *reinterpret_cast<bf16x8*>(p0);
    bf16x8 b = *reinterpret_cast<bf16x8*>(p1);
    bf16x8 oa, ob;
#pragma unroll
    for (int j = 0; j < 8; ++j) {
      float x = (float)a[j], y = (float)b[j];
      oa[j] = (bf16_t)(x * cs[j] - y * sn[j]);
      ob[j] = (bf16_t)(y * cs[j] + x * sn[j]);
    }
    *reinterpret_cast<bf16x8*>(p0) = oa;
    *reinterpret_cast<bf16x8*>(p1) = ob;
  }
}

// ---------------- flash attention: block = (seg, head, 128-row q tile) ----------------
__global__ __launch_bounds__(256) void k_attn(const bf16_t* __restrict__ qkv,
                                              bf16_t* __restrict__ outp) {
  __shared__ __align__(16) bf16_t Ks[64][104];     // also Q staging buffer
  __shared__ __align__(16) bf16_t Vt[80][72];      // V transposed: Vt[d][m]
  __shared__ __align__(16) bf16_t Ps[4][32][72];   // per-wave P tile
  const int qt  = blockIdx.x & 7;
  const int h   = (blockIdx.x >> 3) & 15;
  const int seg = blockIdx.x >> 7;
  const int tid = threadIdx.x, lane = tid & 63, w = tid >> 6;
  const int l15 = lane & 15, lg = lane >> 4;
  const float scale = 0.11180339887498949f;        // 1/sqrt(80)
  const bf16_t* qbase = qkv + (size_t)(seg * LSEQ + qt * 128) * N_QKV + h * 80;
  const bf16_t* kbase = qkv + (size_t)(seg * LSEQ) * N_QKV + DIM + h * 80;
  const bf16_t* vbase = qkv + (size_t)(seg * LSEQ) * N_QKV + 2 * DIM + h * 80;
  const uint4 z4 = {0u, 0u, 0u, 0u};

  // ---- stage Q through Ks (two halves), hold frags in registers ----
  bf16x8 qf[2][3];
#pragma unroll
  for (int half = 0; half < 2; ++half) {
    for (int c = tid; c < 64 * 12; c += 256) {     // cols 0..95 (80..95 zero)
      int r = c / 12, ch = c % 12;
      uint4 v = z4;
      if (ch < 10) v = *reinterpret_cast<const uint4*>(qbase + (size_t)(half * 64 + r) * N_QKV + ch * 8);
      *reinterpret_cast<uint4*>(&Ks[r][ch * 8]) = v;
    }
    __syncthreads();
    if ((w >> 1) == half) {
      const int wr = (w & 1) * 32;
#pragma unroll
      for (int mf = 0; mf < 2; ++mf)
#pragma unroll
        for (int ks = 0; ks < 3; ++ks)
          qf[mf][ks] = *reinterpret_cast<const bf16x8*>(&Ks[wr + mf * 16 + l15][ks * 32 + (lg << 3)]);
    }
    __syncthreads();
  }

  const f32x4 fz = {0.f, 0.f, 0.f, 0.f};
  f32x4 oacc[2][5];
#pragma unroll
  for (int mf = 0; mf < 2; ++mf)
#pragma unroll
    for (int df = 0; df < 5; ++df) oacc[mf][df] = fz;
  float mrun[2][4], lrun[2][4];
#pragma unroll
  for (int mf = 0; mf < 2; ++mf)
#pragma unroll
    for (int r = 0; r < 4; ++r) { mrun[mf][r] = -1e30f; lrun[mf][r] = 0.f; }

  for (int kv0 = 0; kv0 < LSEQ; kv0 += 64) {
    __syncthreads();
    // stage K tile [64][96] (zeros in 80..95)
    for (int c = tid; c < 64 * 12; c += 256) {
      int r = c / 12, ch = c % 12;
      uint4 v = z4;
      if (ch < 10) v = *reinterpret_cast<const uint4*>(kbase + (size_t)(kv0 + r) * N_QKV + ch * 8);
      *reinterpret_cast<uint4*>(&Ks[r][ch * 8]) = v;
    }
    // stage V transposed: Vt[d][m]
    for (int c = tid; c < 64 * 10; c += 256) {
      int r = c / 10, d0 = (c % 10) * 8;
      bf16x8 v = *reinterpret_cast<const bf16x8*>(vbase + (size_t)(kv0 + r) * N_QKV + d0);
#pragma unroll
      for (int j = 0; j < 8; ++j) Vt[d0 + j][r] = v[j];
    }
    __syncthreads();

    // ---- S = Q K^T (per wave: 32 q-rows x 64 kv) ----
    f32x4 sacc[2][4];
#pragma unroll
    for (int mf = 0; mf < 2; ++mf)
#pragma unroll
      for (int nf = 0; nf < 4; ++nf) sacc[mf][nf] = fz;
#pragma unroll
    for (int ks = 0; ks < 3; ++ks) {
      bf16x8 kf[4];
#pragma unroll
      for (int nf = 0; nf < 4; ++nf)
        kf[nf] = *reinterpret_cast<const bf16x8*>(&Ks[nf * 16 + l15][ks * 32 + (lg << 3)]);
#pragma unroll
      for (int mf = 0; mf < 2; ++mf)
#pragma unroll
        for (int nf = 0; nf < 4; ++nf)
          sacc[mf][nf] = __builtin_amdgcn_mfma_f32_16x16x32_bf16(qf[mf][ks], kf[nf], sacc[mf][nf], 0, 0, 0);
    }

    // ---- online softmax (rows spread over 16-lane groups) ----
#pragma unroll
    for (int mf = 0; mf < 2; ++mf) {
#pragma unroll
      for (int r = 0; r < 4; ++r) {
        float mx = -1e30f;
#pragma unroll
        for (int nf = 0; nf < 4; ++nf) {
          sacc[mf][nf][r] *= scale;
          mx = fmaxf(mx, sacc[mf][nf][r]);
        }
        mx = fmaxf(mx, __shfl_xor(mx, 1, 16));
        mx = fmaxf(mx, __shfl_xor(mx, 2, 16));
        mx = fmaxf(mx, __shfl_xor(mx, 4, 16));
        mx = fmaxf(mx, __shfl_xor(mx, 8, 16));
        float mnew = fmaxf(mrun[mf][r], mx);
        float corr = __expf(mrun[mf][r] - mnew);
        mrun[mf][r] = mnew;
        float rs = 0.f;
#pragma unroll
        for (int nf = 0; nf < 4; ++nf) {
          float p = __expf(sacc[mf][nf][r] - mnew);
          sacc[mf][nf][r] = p;
          rs += p;
        }
        rs += __shfl_xor(rs, 1, 16);
        rs += __shfl_xor(rs, 2, 16);
        rs += __shfl_xor(rs, 4, 16);
        rs += __shfl_xor(rs, 8, 16);
        lrun[mf][r] = lrun[mf][r] * corr + rs;
#pragma unroll
        for (int df = 0; df < 5; ++df) oacc[mf][df][r] *= corr;
#pragma unroll
        for (int nf = 0; nf < 4; ++nf)
          Ps[w][mf * 16 + lg * 4 + r][nf * 16 + l15] = (bf16_t)sacc[mf][nf][r];
      }
    }

    // ---- O += P V ----
#pragma unroll
    for (int ks2 = 0; ks2 < 2; ++ks2) {
      bf16x8 pa[2];
#pragma unroll
      for (int mf = 0; mf < 2; ++mf)
        pa[mf] = *reinterpret_cast<const bf16x8*>(&Ps[w][mf * 16 + l15][ks2 * 32 + (lg << 3)]);
#pragma unroll
      for (int df = 0; df < 5; ++df) {
        bf16x8 vv = *reinterpret_cast<const bf16x8*>(&Vt[df * 16 + l15][ks2 * 32 + (lg << 3)]);
#pragma unroll
        for (int mf = 0; mf < 2; ++mf)
          oacc[mf][df] = __builtin_amdgcn_mfma_f32_16x16x32_bf16(pa[mf], vv, oacc[mf][df], 0, 0, 0);
      }
    }
  }

  // ---- epilogue: O / l -> bf16 [S][DIM] ----
#pragma unroll
  for (int mf = 0; mf < 2; ++mf)
#pragma unroll
    for (int r = 0; r < 4; ++r) {
      float inv = 1.0f / lrun[mf][r];
      int row = seg * LSEQ + qt * 128 + w * 32 + mf * 16 + lg * 4 + r;
#pragma unroll
      for (int df = 0; df < 5; ++df)
        outp[(size_t)row * DIM + h * 80 + df * 16 + l15] = (bf16_t)(oacc[mf][df][r] * inv);
    }
}

// ---------------- launch ----------------
extern "C" void kernel_launch(void* const* d_in, const int* in_sizes, int n_in,
                              void* d_out, int out_size, void* d_ws, size_t ws_size,
                              hipStream_t stream) {
  const float* hs    = (const float*)d_in[0];
  const float* cosT  = (const float*)d_in[1];
  const float* sinT  = (const float*)d_in[2];
  const float* Wqkv  = (const float*)d_in[3];
  const float* bqkv  = (const float*)d_in[4];
  const float* Wproj = (const float*)d_in[5];
  const float* bproj = (const float*)d_in[6];
  (void)in_sizes; (void)n_in; (void)out_size; (void)ws_size;

  char* ws = (char*)d_ws;
  bf16_t* hsb  = (bf16_t*)(ws);                    // 8192*1280*2  = 20,971,520
  bf16_t* w1t  = (bf16_t*)(ws + 20971520);         // 3840*1280*2  =  9,830,400
  bf16_t* w2t  = (bf16_t*)(ws + 30801920);         // 1280*1280*2  =  3,276,800
  bf16_t* qkvb = (bf16_t*)(ws + 34078720);         // 8192*3840*2  = 62,914,560
  bf16_t* attn = (bf16_t*)(ws + 96993280);         // 8192*1280*2  = 20,971,520  (total ~118MB)

  k_conv_bf16<<<5120, 256, 0, stream>>>(hs, hsb);
  k_transpose_bf16<<<dim3(120, 40), dim3(32, 8), 0, stream>>>(Wqkv, w1t, 1280, 3840);
  k_transpose_bf16<<<dim3(40, 40), dim3(32, 8), 0, stream>>>(Wproj, w2t, 1280, 1280);
  k_gemm_bt<true><<<1920, 256, 0, stream>>>(hsb, w1t, bqkv, (void*)qkvb, 8192, 3840, 1280);
  k_rope<<<2560, 256, 0, stream>>>(qkvb, cosT, sinT);
  k_attn<<<1024, 256, 0, stream>>>(qkvb, attn);
  k_gemm_bt<false><<<640, 256, 0, stream>>>(attn, w2t, bproj, d_out, 8192, 1280, 1280);
}

// Round 2
// 310.538 us; speedup vs baseline: 1.2952x; 1.2952x over previous
//
#include <hip/hip_runtime.h>
#include <hip/hip_bf16.h>
#include <stdint.h>

typedef __bf16 bf16_t;
typedef __bf16 bf16x8 __attribute__((ext_vector_type(8)));
typedef float f32x4 __attribute__((ext_vector_type(4)));
typedef float f32x16 __attribute__((ext_vector_type(16)));

#define S_TOK 8192
#define DIM   1280
#define NH    16
#define HD    80
#define LSEQ  1024
#define N_QKV 3840

// ---------------- fp32 -> bf16 convert (hidden_states) ----------------
__global__ __launch_bounds__(256) void k_conv_bf16(const float* __restrict__ in,
                                                   bf16_t* __restrict__ out) {
  int g = blockIdx.x * 256 + threadIdx.x;
  const float4* p = reinterpret_cast<const float4*>(in) + (size_t)g * 2;
  float4 v0 = p[0], v1 = p[1];
  bf16x8 o;
  o[0] = (bf16_t)v0.x; o[1] = (bf16_t)v0.y; o[2] = (bf16_t)v0.z; o[3] = (bf16_t)v0.w;
  o[4] = (bf16_t)v1.x; o[5] = (bf16_t)v1.y; o[6] = (bf16_t)v1.z; o[7] = (bf16_t)v1.w;
  *reinterpret_cast<bf16x8*>(out + (size_t)g * 8) = o;
}

// ---------------- W [K][N] fp32 -> Wt [N][K] bf16 ----------------
__global__ __launch_bounds__(256) void k_transpose_bf16(const float* __restrict__ W,
                                                        bf16_t* __restrict__ Wt,
                                                        int K, int N) {
  __shared__ float tile[32][33];
  int n0 = blockIdx.x * 32, k0 = blockIdx.y * 32;
  int tx = threadIdx.x, ty = threadIdx.y;
#pragma unroll
  for (int j = 0; j < 32; j += 8)
    tile[ty + j][tx] = W[(size_t)(k0 + ty + j) * N + n0 + tx];
  __syncthreads();
#pragma unroll
  for (int j = 0; j < 32; j += 8)
    Wt[(size_t)(n0 + ty + j) * K + k0 + tx] = (bf16_t)tile[tx][ty + j];
}

// ---------------- GEMM: C[M][N] = A[M][K] @ Bt[N][K]^T + bias ----------------
template <bool OUT_BF16>
__global__ __launch_bounds__(256) void k_gemm_bt(const bf16_t* __restrict__ A,
                                                 const bf16_t* __restrict__ Bt,
                                                 const float* __restrict__ bias,
                                                 void* __restrict__ Cout,
                                                 int M, int N, int K) {
  __shared__ __align__(16) bf16_t As[128][72];
  __shared__ __align__(16) bf16_t Bs[128][72];
  const int nb = N >> 7;
  const int bm = blockIdx.x / nb, bn = blockIdx.x % nb;
  const int tid = threadIdx.x, lane = tid & 63, w = tid >> 6;
  const int wm = w >> 1, wn = w & 1;
  const int l15 = lane & 15, lg = lane >> 4;
  const f32x4 fz = {0.f, 0.f, 0.f, 0.f};
  f32x4 acc[4][4];
#pragma unroll
  for (int i = 0; i < 4; ++i)
#pragma unroll
    for (int j = 0; j < 4; ++j) acc[i][j] = fz;
  const size_t a0 = (size_t)(bm * 128) * K;
  const size_t b0 = (size_t)(bn * 128) * K;

  for (int k0 = 0; k0 < K; k0 += 64) {
    __syncthreads();
#pragma unroll
    for (int p = 0; p < 4; ++p) {
      int c = tid + p * 256;
      int r = c >> 3, ch = c & 7;
      size_t go = (size_t)r * K + k0 + ch * 8;
      *reinterpret_cast<uint4*>(&As[r][ch * 8]) = *reinterpret_cast<const uint4*>(A + a0 + go);
      *reinterpret_cast<uint4*>(&Bs[r][ch * 8]) = *reinterpret_cast<const uint4*>(Bt + b0 + go);
    }
    __syncthreads();
#pragma unroll
    for (int kk = 0; kk < 2; ++kk) {
      const int krow = kk * 32 + (lg << 3);
      bf16x8 af[4], bfv[4];
#pragma unroll
      for (int mf = 0; mf < 4; ++mf)
        af[mf] = *reinterpret_cast<const bf16x8*>(&As[wm * 64 + mf * 16 + l15][krow]);
#pragma unroll
      for (int nf = 0; nf < 4; ++nf)
        bfv[nf] = *reinterpret_cast<const bf16x8*>(&Bs[wn * 64 + nf * 16 + l15][krow]);
#pragma unroll
      for (int mf = 0; mf < 4; ++mf)
#pragma unroll
        for (int nf = 0; nf < 4; ++nf)
          acc[mf][nf] = __builtin_amdgcn_mfma_f32_16x16x32_bf16(af[mf], bfv[nf], acc[mf][nf], 0, 0, 0);
    }
  }
  const int rg = lg << 2;
#pragma unroll
  for (int nf = 0; nf < 4; ++nf) {
    const int col = bn * 128 + wn * 64 + nf * 16 + l15;
    const float bv = bias[col];
#pragma unroll
    for (int mf = 0; mf < 4; ++mf) {
      const int row0 = bm * 128 + wm * 64 + mf * 16 + rg;
#pragma unroll
      for (int r = 0; r < 4; ++r) {
        float v = acc[mf][nf][r] + bv;
        if (OUT_BF16)
          reinterpret_cast<bf16_t*>(Cout)[(size_t)(row0 + r) * N + col] = (bf16_t)v;
        else
          reinterpret_cast<float*>(Cout)[(size_t)(row0 + r) * N + col] = v;
      }
    }
  }
}

// ---------------- RoPE (in-place; q additionally scaled by 1/sqrt(80)*log2e) ----------------
__global__ __launch_bounds__(256) void k_rope(bf16_t* __restrict__ qkv,
                                              const float* __restrict__ cosT,
                                              const float* __restrict__ sinT) {
  const float QS = 0.11180339887498949f * 1.4426950408889634f;
  int g = blockIdx.x * 256 + threadIdx.x;
  int c = g % 5;
  int h = (g / 5) & 15;
  int s = g / 80;
  const int d0 = c * 8;
  float cs[8], sn[8];
#pragma unroll
  for (int j = 0; j < 8; ++j) {
    cs[j] = cosT[s * 80 + d0 + j];
    sn[j] = sinT[s * 80 + d0 + j];
  }
  size_t base = (size_t)s * N_QKV + h * 80 + d0;
#pragma unroll
  for (int part = 0; part < 2; ++part) {
    const float sc = (part == 0) ? QS : 1.0f;
    bf16_t* p0 = qkv + base + part * 1280;
    bf16_t* p1 = p0 + 40;
    bf16x8 a = *reinterpret_cast<bf16x8*>(p0);
    bf16x8 b = *reinterpret_cast<bf16x8*>(p1);
    bf16x8 oa, ob;
#pragma unroll
    for (int j = 0; j < 8; ++j) {
      float x = (float)a[j], y = (float)b[j];
      oa[j] = (bf16_t)((x * cs[j] - y * sn[j]) * sc);
      ob[j] = (bf16_t)((y * cs[j] + x * sn[j]) * sc);
    }
    *reinterpret_cast<bf16x8*>(p0) = oa;
    *reinterpret_cast<bf16x8*>(p1) = ob;
  }
}

// ---------------- V transpose+permute: vtg[seg][h][d][kv'] = V[seg][swap23(kv')][h][d] ----------------
__global__ __launch_bounds__(256) void k_vtrans(const bf16_t* __restrict__ qkv,
                                                bf16_t* __restrict__ vtg) {
  __shared__ bf16_t T[64][88];
  int sh = blockIdx.x >> 4;            // seg*16 + h
  int kt = blockIdx.x & 15;
  int seg = sh >> 4, h = sh & 15;
  int kv0 = kt * 64;
  int tid = threadIdx.x;
#pragma unroll
  for (int i = 0; i < 3; ++i) {
    int c = tid + i * 256;
    if (c < 640) {
      int r = c / 10, ch = c - r * 10;
      *reinterpret_cast<uint4*>(&T[r][ch * 8]) =
        *reinterpret_cast<const uint4*>(qkv + (size_t)(seg * 1024 + kv0 + r) * N_QKV + 2 * DIM + h * 80 + ch * 8);
    }
  }
  __syncthreads();
#pragma unroll
  for (int i = 0; i < 3; ++i) {
    int c = tid + i * 256;
    if (c < 640) {
      int d = c >> 3, co = c & 7;
      bf16x8 o;
#pragma unroll
      for (int j = 0; j < 8; ++j) {
        int kp = co * 8 + j;
        int kv = (kp & ~12) | (((kp >> 2) & 1) << 3) | (((kp >> 3) & 1) << 2);  // swap bits 2,3
        o[j] = T[kv][d];
      }
      *reinterpret_cast<bf16x8*>(vtg + ((size_t)(sh * 80 + d)) * 1024 + kv0 + co * 8) = o;
    }
  }
}

// ---------------- flash attention v2: swapped QK^T / swapped PV, q-in-lane ----------------
// block = 512 thr (8 warps x 32 q-rows = 256 q-rows), KVBLK=64, double-buffered LDS.
__global__ __launch_bounds__(512, 2) void k_attn2(const bf16_t* __restrict__ qkv,
                                                  const bf16_t* __restrict__ vtg,
                                                  bf16_t* __restrict__ outp) {
  __shared__ __align__(16) char smem[45056];
  bf16_t* KsB = (bf16_t*)smem;                 // 2 x [64][80]   (buf b at b*5120 elems)
  bf16_t* VsB = (bf16_t*)(smem + 20480);       // 2 x [96][64]   (buf b at b*6144 elems)

  const int bid = blockIdx.x;
  const int seg = bid & 7, qt = (bid >> 3) & 3, h = bid >> 5;  // seg-per-XCD decode
  const int tid = threadIdx.x, lane = tid & 63, w = tid >> 6;
  const int l31 = lane & 31, hi = lane >> 5;
  const int q0 = seg * 1024 + qt * 256;

  const bf16_t* kbase = qkv + ((size_t)seg * 1024) * N_QKV + DIM + h * 80;
  const bf16_t* vbase = vtg + ((size_t)(seg * 16 + h) * 80) * 1024;

  // Q fragments (B-operand): lane l31 = q row, hi selects 8-elem half of each 16-d slice
  bf16x8 qf[5];
  {
    const bf16_t* qp = qkv + (size_t)(q0 + w * 32 + l31) * N_QKV + h * 80 + hi * 8;
#pragma unroll
    for (int ks = 0; ks < 5; ++ks) qf[ks] = *reinterpret_cast<const bf16x8*>(qp + ks * 16);
  }

  uint4 kreg[2], vreg[2];
  auto issue = [&](int kv0) {
#pragma unroll
    for (int i = 0; i < 2; ++i) {
      int c = tid + i * 512;
      if (c < 640) {
        int r = c / 10, ch = c - r * 10;
        kreg[i] = *reinterpret_cast<const uint4*>(kbase + (size_t)(kv0 + r) * N_QKV + ch * 8);
      }
    }
#pragma unroll
    for (int i = 0; i < 2; ++i) {
      int c = tid + i * 512;
      if (c < 768) {
        int d = c >> 3, ch = c & 7;
        uint4 v = {0u, 0u, 0u, 0u};
        if (d < 80) v = *reinterpret_cast<const uint4*>(vbase + (size_t)d * 1024 + kv0 + ch * 8);
        vreg[i] = v;
      }
    }
  };
  auto commit = [&](int b) {
    bf16_t* Kb = KsB + b * 5120;
    bf16_t* Vb = VsB + b * 6144;
#pragma unroll
    for (int i = 0; i < 2; ++i) {
      int c = tid + i * 512;
      if (c < 640) *reinterpret_cast<uint4*>(Kb + c * 8) = kreg[i];
    }
#pragma unroll
    for (int i = 0; i < 2; ++i) {
      int c = tid + i * 512;
      if (c < 768) {
        int d = c >> 3, ch = c & 7;
        *reinterpret_cast<uint4*>(Vb + d * 64 + (((ch ^ (d & 7))) << 3)) = vreg[i];
      }
    }
  };

  f32x16 o0, o1, o2;
#pragma unroll
  for (int r = 0; r < 16; ++r) { o0[r] = 0.f; o1[r] = 0.f; o2[r] = 0.f; }
  float mrun = -1e30f, lrun = 0.f;

  issue(0);
  commit(0);
  __syncthreads();
  int cur = 0;

  for (int t = 0; t < 16; ++t) {
    if (t < 15) issue((t + 1) * 64);
    const bf16_t* Kb = KsB + cur * 5120;
    const bf16_t* Vb = VsB + cur * 6144;

    // ---- S^T = K · Q^T  (per-lane: col q = l31, rows kv in regs) ----
    f32x16 st0, st1;
#pragma unroll
    for (int r = 0; r < 16; ++r) { st0[r] = 0.f; st1[r] = 0.f; }
    __builtin_amdgcn_s_setprio(1);
#pragma unroll
    for (int ks = 0; ks < 5; ++ks) {
      bf16x8 k0 = *reinterpret_cast<const bf16x8*>(Kb + l31 * 80 + ks * 16 + hi * 8);
      bf16x8 k1 = *reinterpret_cast<const bf16x8*>(Kb + (32 + l31) * 80 + ks * 16 + hi * 8);
      st0 = __builtin_amdgcn_mfma_f32_32x32x16_bf16(k0, qf[ks], st0, 0, 0, 0);
      st1 = __builtin_amdgcn_mfma_f32_32x32x16_bf16(k1, qf[ks], st1, 0, 0, 0);
    }
    __builtin_amdgcn_s_setprio(0);

    // ---- online softmax, base-2 (scale*log2e folded into Q) ----
    float mx = -1e30f;
#pragma unroll
    for (int r = 0; r < 16; ++r) mx = fmaxf(mx, fmaxf(st0[r], st1[r]));
    mx = fmaxf(mx, __shfl_xor(mx, 32));
    float mnew = fmaxf(mrun, mx);
    float corr = __builtin_exp2f(mrun - mnew);
    float rs = 0.f;
#pragma unroll
    for (int r = 0; r < 16; ++r) { st0[r] = __builtin_exp2f(st0[r] - mnew); rs += st0[r]; }
#pragma unroll
    for (int r = 0; r < 16; ++r) { st1[r] = __builtin_exp2f(st1[r] - mnew); rs += st1[r]; }
    rs += __shfl_xor(rs, 32);
    lrun = lrun * corr + rs;
    mrun = mnew;
#pragma unroll
    for (int r = 0; r < 16; ++r) { o0[r] *= corr; o1[r] *= corr; o2[r] *= corr; }

    // ---- pack P fragments: B-frag(ks2) = regs [ (ks2&1)*8 .. +7 ] of tile (ks2>>1) ----
    bf16x8 pb[4];
#pragma unroll
    for (int u = 0; u < 2; ++u)
#pragma unroll
      for (int j = 0; j < 8; ++j) {
        pb[u][j]     = (bf16_t)st0[u * 8 + j];
        pb[2 + u][j] = (bf16_t)st1[u * 8 + j];
      }

    // ---- O^T += V'^T · P'  (A = V' rows d, B = P fragments; same kv permutation) ----
    __builtin_amdgcn_s_setprio(1);
#pragma unroll
    for (int ks2 = 0; ks2 < 4; ++ks2) {
      {
        int row = l31;
        bf16x8 vf = *reinterpret_cast<const bf16x8*>(Vb + row * 64 + ((((ks2 << 1) + hi) ^ (row & 7)) << 3));
        o0 = __builtin_amdgcn_mfma_f32_32x32x16_bf16(vf, pb[ks2], o0, 0, 0, 0);
      }
      {
        int row = 32 + l31;
        bf16x8 vf = *reinterpret_cast<const bf16x8*>(Vb + row * 64 + ((((ks2 << 1) + hi) ^ (row & 7)) << 3));
        o1 = __builtin_amdgcn_mfma_f32_32x32x16_bf16(vf, pb[ks2], o1, 0, 0, 0);
      }
      {
        int row = 64 + l31;
        bf16x8 vf = *reinterpret_cast<const bf16x8*>(Vb + row * 64 + ((((ks2 << 1) + hi) ^ (row & 7)) << 3));
        o2 = __builtin_amdgcn_mfma_f32_32x32x16_bf16(vf, pb[ks2], o2, 0, 0, 0);
      }
    }
    __builtin_amdgcn_s_setprio(0);

    if (t < 15) commit(cur ^ 1);
    __syncthreads();
    cur ^= 1;
  }

  // ---- epilogue: O^T regs -> LDS transpose -> coalesced global ----
  bf16_t* Osm = (bf16_t*)smem;  // [256][88]
  float inv = 1.0f / lrun;
  const int qrow = w * 32 + l31;
#pragma unroll
  for (int r = 0; r < 16; ++r) {
    int crow = (r & 3) + 8 * (r >> 2) + 4 * hi;
    Osm[qrow * 88 + crow]      = (bf16_t)(o0[r] * inv);
    Osm[qrow * 88 + 32 + crow] = (bf16_t)(o1[r] * inv);
    if (r < 8) Osm[qrow * 88 + 64 + crow] = (bf16_t)(o2[r] * inv);
  }
  __syncthreads();
#pragma unroll
  for (int i = 0; i < 5; ++i) {
    int c = tid + i * 512;
    int q = c / 10, ch = c - q * 10;
    uint4 v = *reinterpret_cast<const uint4*>(Osm + q * 88 + ch * 8);
    *reinterpret_cast<uint4*>(outp + (size_t)(q0 + q) * DIM + h * 80 + ch * 8) = v;
  }
}

// ---------------- launch ----------------
extern "C" void kernel_launch(void* const* d_in, const int* in_sizes, int n_in,
                              void* d_out, int out_size, void* d_ws, size_t ws_size,
                              hipStream_t stream) {
  const float* hs    = (const float*)d_in[0];
  const float* cosT  = (const float*)d_in[1];
  const float* sinT  = (const float*)d_in[2];
  const float* Wqkv  = (const float*)d_in[3];
  const float* bqkv  = (const float*)d_in[4];
  const float* Wproj = (const float*)d_in[5];
  const float* bproj = (const float*)d_in[6];
  (void)in_sizes; (void)n_in; (void)out_size; (void)ws_size;

  char* ws = (char*)d_ws;
  bf16_t* hsb  = (bf16_t*)(ws);                    // 20,971,520 B (reused as vtg after GEMM)
  bf16_t* w1t  = (bf16_t*)(ws + 20971520);         //  9,830,400
  bf16_t* w2t  = (bf16_t*)(ws + 30801920);         //  3,276,800
  bf16_t* qkvb = (bf16_t*)(ws + 34078720);         // 62,914,560
  bf16_t* attn = (bf16_t*)(ws + 96993280);         // 20,971,520
  bf16_t* vtg  = hsb;                              // vtg[128][80][1024] = 20,971,520 (hsb dead post-GEMM)

  k_conv_bf16<<<5120, 256, 0, stream>>>(hs, hsb);
  k_transpose_bf16<<<dim3(120, 40), dim3(32, 8), 0, stream>>>(Wqkv, w1t, 1280, 3840);
  k_transpose_bf16<<<dim3(40, 40), dim3(32, 8), 0, stream>>>(Wproj, w2t, 1280, 1280);
  k_gemm_bt<true><<<1920, 256, 0, stream>>>(hsb, w1t, bqkv, (void*)qkvb, 8192, 3840, 1280);
  k_rope<<<2560, 256, 0, stream>>>(qkvb, cosT, sinT);
  k_vtrans<<<2048, 256, 0, stream>>>(qkvb, vtg);
  k_attn2<<<512, 512, 0, stream>>>(qkvb, vtg, attn);
  k_gemm_bt<false><<<640, 256, 0, stream>>>(attn, w2t, bproj, d_out, 8192, 1280, 1280);
}